// Round 3
// baseline (1224.282 us; speedup 1.0000x reference)
//
#include <hip/hip_runtime.h>

typedef _Float16 f16;
typedef _Float16 f16x8 __attribute__((ext_vector_type(8)));
typedef float    f32x4 __attribute__((ext_vector_type(4)));

#define MFMA16(a,b,c) __builtin_amdgcn_mfma_f32_16x16x32_f16(a,b,c,0,0,0)

#define HIST_S 1096   // per-sample stride in hist (8*136 + 8 pad), *2B = 2192 (16B aligned, bank-skewed)
#define HB_S   136    // per-sample stride in hb1 (128 + 8 pad), *2B = 272 (16B aligned)
#define HB_BUF 4352   // 32*HB_S

__device__ __forceinline__ float sigm(float v){
  return __builtin_amdgcn_rcpf(1.f + __builtin_amdgcn_exp2f(-1.4426950408889634f*v));
}
__device__ __forceinline__ float tanha(float v){
  return 1.f - 2.f*__builtin_amdgcn_rcpf(1.f + __builtin_amdgcn_exp2f(2.8853900817779268f*v));
}
__device__ __forceinline__ f32x4 splat4(float v){ f32x4 r; r[0]=v;r[1]=v;r[2]=v;r[3]=v; return r; }

// 8 consecutive f32 from row-major W[n][k] at (n,k0) -> f16 B-fragment (n=lane&15, k=k0..k0+7)
__device__ __forceinline__ f16x8 ldfrag(const float* __restrict__ W, int K, int n, int k0){
  const float* p = W + n*K + k0;
  f32x4 a = *(const f32x4*)p;
  f32x4 b = *(const f32x4*)(p+4);
  f16x8 r;
  #pragma unroll
  for (int i=0;i<4;i++){ r[i] = (f16)a[i]; r[4+i] = (f16)b[i]; }
  return r;
}
// K=60 rows, zero-pad k>=60 (only k0==56 crosses the edge)
__device__ __forceinline__ f16x8 ldfrag60(const float* __restrict__ W, int n, int k0){
  const float* p = W + n*60 + k0;
  f32x4 a = *(const f32x4*)p;
  f16x8 r;
  #pragma unroll
  for (int i=0;i<4;i++) r[i] = (f16)a[i];
  if (k0 < 56){
    f32x4 b = *(const f32x4*)(p+4);
    #pragma unroll
    for (int i=0;i<4;i++) r[4+i] = (f16)b[i];
  } else {
    #pragma unroll
    for (int i=0;i<4;i++) r[4+i] = (f16)0.f;
  }
  return r;
}
__device__ __forceinline__ f16x8 zfrag(){
  f16x8 r;
  #pragma unroll
  for (int i=0;i<8;i++) r[i] = (f16)0.f;
  return r;
}

// gate nonlinearities + c/h update; writes h (f16) to dst[(m*16+qd*4+r)*stride + col]
__device__ __forceinline__ void act_update(f32x4 acc[2][4], f32x4* cst, f16* dst, int stride, int col, int qd){
  #pragma unroll
  for (int m=0;m<2;m++){
    #pragma unroll
    for (int r=0;r<4;r++){
      float ii = sigm(acc[m][0][r]);
      float ff = sigm(acc[m][1][r]);
      float gg = tanha(acc[m][2][r]);
      float oo = sigm(acc[m][3][r]);
      float cn = ff*cst[m][r] + ii*gg;
      cst[m][r] = cn;
      dst[(m*16+qd*4+r)*stride + col] = (f16)(oo*tanha(cn));
    }
  }
}

__global__ void __launch_bounds__(512, 2)
lstm_main(const float* __restrict__ x,
          const float* __restrict__ e0Wih, const float* __restrict__ e0Whh, const float* __restrict__ e0bi, const float* __restrict__ e0bh,
          const float* __restrict__ e1Wih, const float* __restrict__ e1Whh, const float* __restrict__ e1bi, const float* __restrict__ e1bh,
          const float* __restrict__ d0Wih, const float* __restrict__ d0Whh, const float* __restrict__ d0bi, const float* __restrict__ d0bh,
          const float* __restrict__ d1Wih, const float* __restrict__ d1Whh, const float* __restrict__ d1bi, const float* __restrict__ d1bh,
          const float* __restrict__ Wlat,  const float* __restrict__ blat,
          const float* __restrict__ Wout,  const float* __restrict__ bout,
          float* __restrict__ out)
{
  __shared__ __align__(16) f16 hist[32*HIST_S];  // 70144 B: h0 history (enc), then d0 history (dec)
  __shared__ __align__(16) f16 hb1 [2*HB_BUF];   // 17408 B: double-buffered h1 / h_d1 (+ z scratch)

  const int tid = threadIdx.x;
  const int w   = tid >> 6;        // wave 0..7
  const int ln  = tid & 15;        // A-row / B-col / C-col within 16-tile
  const int qd  = (tid >> 4) & 3;  // quad
  const int bs  = blockIdx.x << 5; // 32 samples per WG
  const int col = w*16 + ln;       // unit index within gate, 0..127

  f16x8 Bf[4][8];
  f32x4 acc[2][4];
  f32x4 cst[2];
  float bg[4];

  // ===================== P1: encoder layer 0 (K = 64(x,pad) + 128(h0)) ====
  #pragma unroll
  for (int g=0;g<4;g++){
    const int n = g*128 + col;
    #pragma unroll
    for (int kb=0;kb<2;kb++) Bf[g][kb]   = ldfrag60(e0Wih, n, kb*32 + qd*8);
    #pragma unroll
    for (int kb=0;kb<4;kb++) Bf[g][kb+2] = ldfrag(e0Whh, 128, n, kb*32 + qd*8);
    bg[g] = e0bi[n] + e0bh[n];
  }
  cst[0] = splat4(0.f); cst[1] = splat4(0.f);
  for (int t=0; t<8; t++){
    #pragma unroll
    for (int m=0;m<2;m++)
      #pragma unroll
      for (int g=0;g<4;g++) acc[m][g] = splat4(bg[g]);
    #pragma unroll
    for (int kb=0; kb<2; kb++){        // x part, A from global f32 -> f16
      #pragma unroll
      for (int m=0;m<2;m++){
        const float* p = x + (bs + m*16 + ln)*480 + t*60 + kb*32 + qd*8;
        f16x8 a;
        {
          f32x4 lo = *(const f32x4*)p;
          #pragma unroll
          for (int i=0;i<4;i++) a[i] = (f16)lo[i];
          if (kb==1 && qd==3){
            #pragma unroll
            for (int i=0;i<4;i++) a[4+i] = (f16)0.f;   // k=60..63 pad
          } else {
            f32x4 hi = *(const f32x4*)(p+4);
            #pragma unroll
            for (int i=0;i<4;i++) a[4+i] = (f16)hi[i];
          }
        }
        #pragma unroll
        for (int g=0; g<4; g++) acc[m][g] = MFMA16(a, Bf[g][kb], acc[m][g]);
      }
    }
    if (t > 0){                        // h0_{t-1}
      #pragma unroll
      for (int kb=0; kb<4; kb++){
        #pragma unroll
        for (int m=0;m<2;m++){
          f16x8 a = *(const f16x8*)(hist + (m*16+ln)*HIST_S + (t-1)*HB_S + kb*32 + qd*8);
          #pragma unroll
          for (int g=0; g<4; g++) acc[m][g] = MFMA16(a, Bf[g][kb+2], acc[m][g]);
        }
      }
    }
    act_update(acc, cst, hist + t*HB_S, HIST_S, col, qd);
    __syncthreads();
  }

  // ===================== P2: encoder layer 1 (K = 128(h0_t) + 128(h1)) ====
  #pragma unroll
  for (int g=0;g<4;g++){
    const int n = g*128 + col;
    #pragma unroll
    for (int kb=0;kb<4;kb++){
      Bf[g][kb]   = ldfrag(e1Wih, 128, n, kb*32 + qd*8);
      Bf[g][kb+4] = ldfrag(e1Whh, 128, n, kb*32 + qd*8);
    }
    bg[g] = e1bi[n] + e1bh[n];
  }
  cst[0] = splat4(0.f); cst[1] = splat4(0.f);
  for (int t=0; t<8; t++){
    #pragma unroll
    for (int m=0;m<2;m++)
      #pragma unroll
      for (int g=0;g<4;g++) acc[m][g] = splat4(bg[g]);
    #pragma unroll
    for (int kb=0; kb<4; kb++){        // h0_t
      #pragma unroll
      for (int m=0;m<2;m++){
        f16x8 a = *(const f16x8*)(hist + (m*16+ln)*HIST_S + t*HB_S + kb*32 + qd*8);
        #pragma unroll
        for (int g=0; g<4; g++) acc[m][g] = MFMA16(a, Bf[g][kb], acc[m][g]);
      }
    }
    if (t > 0){                        // h1_{t-1}
      const f16* hb = hb1 + ((t-1)&1)*HB_BUF;
      #pragma unroll
      for (int kb=0; kb<4; kb++){
        #pragma unroll
        for (int m=0;m<2;m++){
          f16x8 a = *(const f16x8*)(hb + (m*16+ln)*HB_S + kb*32 + qd*8);
          #pragma unroll
          for (int g=0; g<4; g++) acc[m][g] = MFMA16(a, Bf[g][kb+4], acc[m][g]);
        }
      }
    }
    act_update(acc, cst, hb1 + (t&1)*HB_BUF, HB_S, col, qd);
    __syncthreads();
  }

  // ===================== P3a: z = h_last @ Wlat^T + blat -> zbuf (buf0) ===
  {
    const int mo = w & 1, no = w >> 1;    // 2 m-tiles x 4 n-tiles across 8 waves
    const int zn = no*16 + ln;            // latent index 0..63
    f32x4 zacc = splat4(blat[zn]);
    f16x8 Bz[4];
    #pragma unroll
    for (int kb=0;kb<4;kb++) Bz[kb] = ldfrag(Wlat, 128, zn, kb*32 + qd*8);
    const f16* hb = hb1 + HB_BUF;         // h_last = h1 at t=7 (buffer 1)
    #pragma unroll
    for (int kb=0;kb<4;kb++){
      f16x8 a = *(const f16x8*)(hb + (mo*16+ln)*HB_S + kb*32 + qd*8);
      zacc = MFMA16(a, Bz[kb], zacc);
    }
    #pragma unroll
    for (int r=0;r<4;r++)
      hb1[(mo*16+qd*4+r)*HB_S + zn] = (f16)zacc[r];    // zbuf = buf0 (free)
  }
  __syncthreads();

  // ===================== P3b: xg_dec0 = z @ d0Wih^T + (d0bi+d0bh) =========
  f32x4 xga[2][4];                        // fp32, lives through P4
  {
    f16x8 Bd[4][2];
    #pragma unroll
    for (int g=0;g<4;g++){
      const int n = g*128 + col;
      #pragma unroll
      for (int kb=0;kb<2;kb++) Bd[g][kb] = ldfrag(d0Wih, 64, n, kb*32 + qd*8);
      float bgd = d0bi[n] + d0bh[n];
      xga[0][g] = splat4(bgd); xga[1][g] = splat4(bgd);
    }
    #pragma unroll
    for (int kb=0; kb<2; kb++){
      #pragma unroll
      for (int m=0;m<2;m++){
        f16x8 a = *(const f16x8*)(hb1 + (m*16+ln)*HB_S + kb*32 + qd*8);  // z
        #pragma unroll
        for (int g=0; g<4; g++) xga[m][g] = MFMA16(a, Bd[g][kb], xga[m][g]);
      }
    }
  }

  // ===================== P4: decoder layer 0 (K = 128, init = xg) =========
  #pragma unroll
  for (int g=0;g<4;g++){
    const int n = g*128 + col;
    #pragma unroll
    for (int kb=0;kb<4;kb++) Bf[g][kb] = ldfrag(d0Whh, 128, n, kb*32 + qd*8);
  }
  cst[0] = splat4(0.f); cst[1] = splat4(0.f);
  for (int t=0; t<8; t++){
    #pragma unroll
    for (int m=0;m<2;m++)
      #pragma unroll
      for (int g=0;g<4;g++) acc[m][g] = xga[m][g];
    if (t > 0){
      #pragma unroll
      for (int kb=0; kb<4; kb++){
        #pragma unroll
        for (int m=0;m<2;m++){
          f16x8 a = *(const f16x8*)(hist + (m*16+ln)*HIST_S + (t-1)*HB_S + kb*32 + qd*8);
          #pragma unroll
          for (int g=0; g<4; g++) acc[m][g] = MFMA16(a, Bf[g][kb], acc[m][g]);
        }
      }
    }
    act_update(acc, cst, hist + t*HB_S, HIST_S, col, qd);  // d0 history overwrites enc history
    __syncthreads();
  }

  // ===================== P5: decoder layer 1 + output projection ==========
  #pragma unroll
  for (int g=0;g<4;g++){
    const int n = g*128 + col;
    #pragma unroll
    for (int kb=0;kb<4;kb++){
      Bf[g][kb]   = ldfrag(d1Wih, 128, n, kb*32 + qd*8);
      Bf[g][kb+4] = ldfrag(d1Whh, 128, n, kb*32 + qd*8);
    }
    bg[g] = d1bi[n] + d1bh[n];
  }
  const int dcol = (w>>1)*16 + ln;   // output feature index 0..63
  const int mo   = w & 1;            // out-proj m-tile for this wave
  f16x8 BO[4];
  #pragma unroll
  for (int kb=0;kb<4;kb++)
    BO[kb] = (dcol < 60) ? ldfrag(Wout, 128, dcol, kb*32 + qd*8) : zfrag();
  const float bo = (dcol < 60) ? bout[dcol] : 0.f;
  cst[0] = splat4(0.f); cst[1] = splat4(0.f);
  for (int t=0; t<8; t++){
    #pragma unroll
    for (int m=0;m<2;m++)
      #pragma unroll
      for (int g=0;g<4;g++) acc[m][g] = splat4(bg[g]);
    #pragma unroll
    for (int kb=0; kb<4; kb++){        // h_d0_t
      #pragma unroll
      for (int m=0;m<2;m++){
        f16x8 a = *(const f16x8*)(hist + (m*16+ln)*HIST_S + t*HB_S + kb*32 + qd*8);
        #pragma unroll
        for (int g=0; g<4; g++) acc[m][g] = MFMA16(a, Bf[g][kb], acc[m][g]);
      }
    }
    if (t > 0){                        // h_d1_{t-1}
      const f16* hb = hb1 + ((t-1)&1)*HB_BUF;
      #pragma unroll
      for (int kb=0; kb<4; kb++){
        #pragma unroll
        for (int m=0;m<2;m++){
          f16x8 a = *(const f16x8*)(hb + (m*16+ln)*HB_S + kb*32 + qd*8);
          #pragma unroll
          for (int g=0; g<4; g++) acc[m][g] = MFMA16(a, Bf[g][kb+4], acc[m][g]);
        }
      }
    }
    act_update(acc, cst, hb1 + (t&1)*HB_BUF, HB_S, col, qd);
    __syncthreads();
    // ---- out_t = h_d1_t @ W_out^T + b_out (each wave: 1 m-tile x 1 n-tile)
    f32x4 ao = splat4(bo);
    const f16* hb2 = hb1 + (t&1)*HB_BUF + (mo*16+ln)*HB_S + qd*8;
    #pragma unroll
    for (int kb=0; kb<4; kb++){
      f16x8 a = *(const f16x8*)(hb2 + kb*32);
      ao = MFMA16(a, BO[kb], ao);
    }
    if (dcol < 60){
      #pragma unroll
      for (int r=0;r<4;r++){
        int s = mo*16 + qd*4 + r;
        out[(bs + s)*480 + t*60 + dcol] = ao[r];
      }
    }
  }
}

// ---------------- host launch ---------------------------------------------
extern "C" void kernel_launch(void* const* d_in, const int* in_sizes, int n_in,
                              void* d_out, int out_size, void* d_ws, size_t ws_size,
                              hipStream_t stream)
{
  (void)d_ws; (void)ws_size; (void)in_sizes; (void)n_in; (void)out_size;
  hipLaunchKernelGGL(lstm_main, dim3(2048), dim3(512), 0, stream,
                     (const float*)d_in[0],
                     (const float*)d_in[1],  (const float*)d_in[2],  (const float*)d_in[3],  (const float*)d_in[4],
                     (const float*)d_in[5],  (const float*)d_in[6],  (const float*)d_in[7],  (const float*)d_in[8],
                     (const float*)d_in[9],  (const float*)d_in[10], (const float*)d_in[11], (const float*)d_in[12],
                     (const float*)d_in[13], (const float*)d_in[14], (const float*)d_in[15], (const float*)d_in[16],
                     (const float*)d_in[17], (const float*)d_in[18],
                     (const float*)d_in[19], (const float*)d_in[20],
                     (float*)d_out);
}